// Round 2
// baseline (4285.645 us; speedup 1.0000x reference)
//
#include <hip/hip_runtime.h>
#include <math.h>

#define TT 128
#define NF 512
#define HH 1024
#define WROWS (NF + HH)  // 1536
#define SPIN_LIMIT (1 << 22)  // bounded spin: hang -> wrong answer, not dead container

// ---------------- Phase 1: acc[t][j] = bs[t][j] + sum_{k<512} x[t][k]*W[t][k][j]
// grid = 128 t * 4 quarters, block = 256. Also zeroes cnt/ready flags.
__global__ __launch_bounds__(256) void pg_phase1(
    const float* __restrict__ x, const float* __restrict__ Ws,
    const float* __restrict__ bs, float* __restrict__ acc,
    int* __restrict__ cnt, int* __restrict__ ready) {
  const int t = blockIdx.x >> 2;
  const int q = blockIdx.x & 3;
  const int tid = threadIdx.x;
  __shared__ float xs[NF];
  xs[tid] = x[t * NF + tid];
  xs[tid + 256] = x[t * NF + tid + 256];
  if (q == 0 && tid < 32) cnt[t * 32 + tid] = 0;
  if (q == 1 && tid < 32) ready[t * 32 + tid] = 0;
  __syncthreads();
  const int j = q * 256 + tid;
  const float* w = Ws + (size_t)t * WROWS * HH + j;
  float s = bs[t * HH + j];
#pragma unroll 8
  for (int k = 0; k < NF; ++k) s += xs[k] * w[(size_t)k * HH];
  acc[t * HH + j] = s;
}

// ---------------- Phase 2: sequential recurrence, persistent 256 blocks.
// block b: colgroup g = b&31 (32 cols), rowgroup r = b>>5 (128 rows of h).
// Per step: partial = W_h[t][rows, cols]^T h[rows]; atomicAdd into acc[t];
// 8th arriver tanh's and publishes h chunk + release flag. Weights for step
// t+1 are prefetched into registers BEFORE waiting on step t-1's flags, so
// HBM streaming overlaps the serial sync chain.
__global__ __launch_bounds__(256) void pg_phase2(
    const float* __restrict__ h_in, const float* __restrict__ Ws,
    const float* __restrict__ Wout, const float* __restrict__ bout,
    float* __restrict__ acc, float* __restrict__ h_buf,
    int* __restrict__ cnt, int* __restrict__ ready,
    float* __restrict__ out) {
  const int tid = threadIdx.x;
  const int g = blockIdx.x & 31;
  const int r = blockIdx.x >> 5;
  const int c4 = tid & 7;   // which float4 within the 32-col group
  const int rw = tid >> 3;  // 0..31 thread-row
  const int j0 = g * 32 + c4 * 4;

  __shared__ float hs[128];
  __shared__ float pacc[32][33];
  __shared__ int last_flag;

  const size_t WSTEP = (size_t)WROWS * HH;
  // base: skip x-rows (512), add this thread's first row and col offset
  const float* Wb = Ws + (size_t)NF * HH + (size_t)(r * 128 + rw) * HH + j0;

  // prefetch W slice for t=0 (rows rw, rw+32, rw+64, rw+96 of this rowgroup)
  float4 wb0 = *(const float4*)(Wb);
  float4 wb1 = *(const float4*)(Wb + 32 * HH);
  float4 wb2 = *(const float4*)(Wb + 64 * HH);
  float4 wb3 = *(const float4*)(Wb + 96 * HH);

  for (int t = 0; t < TT; ++t) {
    float4 w0 = wb0, w1 = wb1, w2 = wb2, w3 = wb3;
    // prefetch next step's weights BEFORE waiting on h (overlaps sync chain)
    if (t + 1 < TT) {
      const float* p = Wb + (size_t)(t + 1) * WSTEP;
      wb0 = *(const float4*)(p);
      wb1 = *(const float4*)(p + 32 * HH);
      wb2 = *(const float4*)(p + 64 * HH);
      wb3 = *(const float4*)(p + 96 * HH);
    }
    if (t == 0) {
      if (tid < 128) hs[tid] = h_in[r * 128 + tid];
      __syncthreads();
    } else {
      if (tid < 4) {
        const int* f = &ready[(t - 1) * 32 + r * 4 + tid];
        int guard = 0;
        while (__hip_atomic_load(f, __ATOMIC_ACQUIRE,
                                 __HIP_MEMORY_SCOPE_AGENT) == 0 &&
               ++guard < SPIN_LIMIT)
          __builtin_amdgcn_s_sleep(1);
      }
      __syncthreads();  // A: flags seen before h loads
      if (tid < 128)
        hs[tid] = __hip_atomic_load(
            &h_buf[(size_t)(t - 1) * HH + r * 128 + tid], __ATOMIC_RELAXED,
            __HIP_MEMORY_SCOPE_AGENT);
      __syncthreads();  // B: hs staged
    }

    const float h0 = hs[rw], h1 = hs[rw + 32], h2 = hs[rw + 64],
                h3 = hs[rw + 96];
    pacc[rw][c4 * 4 + 0] = h0 * w0.x + h1 * w1.x + h2 * w2.x + h3 * w3.x;
    pacc[rw][c4 * 4 + 1] = h0 * w0.y + h1 * w1.y + h2 * w2.y + h3 * w3.y;
    pacc[rw][c4 * 4 + 2] = h0 * w0.z + h1 * w1.z + h2 * w2.z + h3 * w3.z;
    pacc[rw][c4 * 4 + 3] = h0 * w0.w + h1 * w1.w + h2 * w2.w + h3 * w3.w;
    __syncthreads();  // C: partials in LDS

    if (tid < 32) {
      float s = 0.f;
#pragma unroll
      for (int rr = 0; rr < 32; ++rr) s += pacc[rr][tid];
      atomicAdd(&acc[(size_t)t * HH + g * 32 + tid], s);
    }
    if (tid == 0) {
      // acq_rel fetch_add orders this wave's prior atomic adds
      int old = __hip_atomic_fetch_add(&cnt[t * 32 + g], 1, __ATOMIC_ACQ_REL,
                                       __HIP_MEMORY_SCOPE_AGENT);
      last_flag = (old == 7);
    }
    __syncthreads();  // D: last_flag visible, pacc consumed

    if (last_flag) {  // block-uniform
      if (tid < 32) {
        float v = __hip_atomic_load(&acc[(size_t)t * HH + g * 32 + tid],
                                    __ATOMIC_RELAXED, __HIP_MEMORY_SCOPE_AGENT);
        float hv = tanhf(v);
        __hip_atomic_store(&h_buf[(size_t)t * HH + g * 32 + tid], hv,
                           __ATOMIC_RELAXED, __HIP_MEMORY_SCOPE_AGENT);
      }
      __threadfence();
      if (tid == 0)
        __hip_atomic_store(&ready[t * 32 + g], 1, __ATOMIC_RELEASE,
                           __HIP_MEMORY_SCOPE_AGENT);
    }
  }

  // Final epilogue: block 0 writes h_final and actors
  if (blockIdx.x == 0) {
    if (tid < 32) {
      const int* f = &ready[(TT - 1) * 32 + tid];
      int guard = 0;
      while (__hip_atomic_load(f, __ATOMIC_ACQUIRE,
                               __HIP_MEMORY_SCOPE_AGENT) == 0 &&
             ++guard < SPIN_LIMIT)
        __builtin_amdgcn_s_sleep(1);
    }
    __syncthreads();
    float a0 = 0.f, a1 = 0.f;
#pragma unroll
    for (int i = 0; i < 4; ++i) {
      int k = tid + 256 * i;
      float v = __hip_atomic_load(&h_buf[(size_t)(TT - 1) * HH + k],
                                  __ATOMIC_RELAXED, __HIP_MEMORY_SCOPE_AGENT);
      out[2 + k] = v;
      a0 += v * Wout[k * 2 + 0];
      a1 += v * Wout[k * 2 + 1];
    }
    float* red = &pacc[0][0];  // reuse LDS (1056 floats >= 512)
    red[tid] = a0;
    red[256 + tid] = a1;
    __syncthreads();
    for (int s = 128; s > 0; s >>= 1) {
      if (tid < s) {
        red[tid] += red[tid + s];
        red[256 + tid] += red[256 + tid + s];
      }
      __syncthreads();
    }
    if (tid == 0) {
      out[0] = red[0] + bout[0];
      out[1] = red[256] + bout[1];
    }
  }
}

extern "C" void kernel_launch(void* const* d_in, const int* in_sizes, int n_in,
                              void* d_out, int out_size, void* d_ws,
                              size_t ws_size, hipStream_t stream) {
  const float* x = (const float*)d_in[0];
  const float* h = (const float*)d_in[1];
  const float* Ws = (const float*)d_in[2];
  const float* bs = (const float*)d_in[3];
  const float* Wout = (const float*)d_in[4];
  const float* bout = (const float*)d_in[5];
  float* out = (float*)d_out;

  // workspace layout
  float* acc = (float*)d_ws;            // TT*HH floats (pre-activations)
  float* h_buf = acc + TT * HH;         // TT*HH floats (published h per step)
  int* cnt = (int*)(h_buf + TT * HH);   // TT*32 arrival counters
  int* ready = cnt + TT * 32;           // TT*32 ready flags

  pg_phase1<<<dim3(TT * 4), dim3(256), 0, stream>>>(x, Ws, bs, acc, cnt,
                                                    ready);
  pg_phase2<<<dim3(256), dim3(256), 0, stream>>>(h, Ws, Wout, bout, acc, h_buf,
                                                 cnt, ready, out);
}